// Round 13
// baseline (274.643 us; speedup 1.0000x reference)
//
#include <hip/hip_runtime.h>

#define BATCH 8
#define SEQ   8192
#define NH    16
#define DP    64
#define DN    64
#define ROWF  (NH*DP)        // 1024 floats = 4KB per t (all heads)
#define NTHR  1024           // 16 waves; wave w <-> head w
#define TROWS 8              // t-rows per tile: 8 x 4KB = 32KB per array

typedef const __attribute__((address_space(1))) void* gptr_t;
typedef __attribute__((address_space(3))) void* lptr_t;

// ---------------------------------------------------------------------------
// k_partial: block = (b, chunk), covering ALL 16 heads -> the block's global
// reads are a fully CONTIGUOUS 1MB X stream + 1MB B stream (consecutive
// 4KB t-rows). Every prior decomposition fixed h per block/wave => 256B-2KB
// granules at 4KB stride, and ALL capped at 2.4-2.9 TB/s delivered
// (r2,5,8,10,11,12 - invariant across staging styles, occupancy, barriers;
// r12's barrier-free version even regressed). Largest-granule variant (r3,
// 2KB) gave the best BW (3.44 TB/s) -> granule/page-locality is the cap.
// Wave w owns head w's full 64x64 state; LDS broadcast serves all waves.
// partial[p][n] = sum_t exp(chunkTotal - cumsum_t) * X[t][p] * B[t][n]
// ---------------------------------------------------------------------------
template<int NBLK>
__global__ __launch_bounds__(NTHR)   // no 2nd arg: natural VGPR (~90), r10 law
void k_partial(const float* __restrict__ Xg, const float* __restrict__ Ag,
               const float* __restrict__ Bg, float* __restrict__ part,
               float* __restrict__ blockA)
{
    constexpr int TB    = SEQ / NBLK;   // 256 (NBLK=32) or 512 (NBLK=16)
    constexpr int Q     = TB / 64;      // A-values per lane in the scan: 4 or 8
    constexpr int NTILE = TB / TROWS;   // 32 or 64

    __shared__ float sX[2][TROWS][ROWF];   // 2 x 32 KB
    __shared__ float sB[2][TROWS][ROWF];   // 2 x 32 KB  (128 KB -> 1 block/CU)

    const int gid  = blockIdx.x;             // b*NBLK + blk
    const int blk  = gid % NBLK;
    const int b    = gid / NBLK;
    const int tid  = threadIdx.x;
    const int wave = tid >> 6;               // 0..15 == head
    const int lane = tid & 63;
    const int t0   = blk * TB;

    // ---- per-wave scan of A column h=wave over this chunk ----
    float c[Q];
    {
        const size_t abase = ((size_t)(b * SEQ + t0 + lane * Q)) * NH + wave;
        float run = 0.f;
        #pragma unroll
        for (int k = 0; k < Q; ++k) { run += Ag[abase + (size_t)k * NH]; c[k] = run; }
    }
    float tsum = c[Q - 1], s = tsum;
    #pragma unroll
    for (int d = 1; d < 64; d <<= 1) {
        float o = __shfl_up(s, d, 64);
        if (lane >= d) s += o;
    }
    const float total = __shfl(s, 63, 64);
    const float excl  = s - tsum;
    float wv[Q];                             // weights stay in registers
    #pragma unroll
    for (int k = 0; k < Q; ++k) wv[k] = __expf(total - (excl + c[k]));
    if (lane == 63) blockA[(size_t)(b * NH + wave) * NBLK + blk] = total;

    // ---- accumulator ----
    float acc[8][8];
    #pragma unroll
    for (int i = 0; i < 8; ++i)
        #pragma unroll
        for (int j = 0; j < 8; ++j) acc[i][j] = 0.f;

    const int p0F = (lane >> 3) << 3;        // 8x8 per-lane tile of the 64x64 state
    const int n0F = (lane & 7) << 3;
    const int lo4 = lane * 4;                // lane's 16B within a 1KB segment
    const size_t trow0 = (size_t)(b * SEQ + t0) * ROWF;

    // per tile: 64KB = 64 x 1KB wave-loads; wave w issues units w*4..w*4+3.
    // units 0-31 -> X (row=u>>2, seg=u&3), 32-63 -> B.
    auto stage = [&](int tile, int buf) {
        const int tt = tile % NTILE;                   // wrap on last iter
        const size_t tb = trow0 + (size_t)(tt * TROWS) * ROWF;
        #pragma unroll
        for (int q = 0; q < 4; ++q) {
            const int u   = wave * 4 + q;
            const int row = (u >> 2) & 7;
            const int seg = u & 3;
            const size_t off = tb + (size_t)row * ROWF + seg * 256 + lo4;
            if (u < 32)
                __builtin_amdgcn_global_load_lds((gptr_t)(Xg + off),
                                                 (lptr_t)&sX[buf][row][seg * 256], 16, 0, 0);
            else
                __builtin_amdgcn_global_load_lds((gptr_t)(Bg + off),
                                                 (lptr_t)&sB[buf][row][seg * 256], 16, 0, 0);
        }
    };

    stage(0, 0);
    for (int tile = 0; tile < NTILE; ++tile) {
        const int buf = tile & 1;
        // all 16 waves done reading buf^1 before overwrite
        asm volatile("s_waitcnt lgkmcnt(0)" ::: "memory");
        __builtin_amdgcn_s_barrier();
        stage((tile + 1) % NTILE, buf ^ 1);
        // wait own 4 loads of CURRENT tile; next tile's 4 stay in flight
        asm volatile("s_waitcnt vmcnt(4)" ::: "memory");
        __builtin_amdgcn_s_barrier();                  // tile visible to all

        #pragma unroll
        for (int tt = 0; tt < TROWS; ++tt) {
            const int tglob = tile * TROWS + tt;
            const int srcl  = tglob / Q;                       // uniform lane index
            const float wt  = __shfl(wv[tt & (Q - 1)], srcl, 64);
            const float* rx  = &sX[buf][tt][wave * 64];
            const float* rbp = &sB[buf][tt][wave * 64];
            const float4 xa = *(const float4*)&rx[p0F];
            const float4 xb = *(const float4*)&rx[p0F + 4];
            const float4 ba = *(const float4*)&rbp[n0F];
            const float4 bb = *(const float4*)&rbp[n0F + 4];
            const float xs[8] = { xa.x * wt, xa.y * wt, xa.z * wt, xa.w * wt,
                                  xb.x * wt, xb.y * wt, xb.z * wt, xb.w * wt };
            const float bs[8] = { ba.x, ba.y, ba.z, ba.w, bb.x, bb.y, bb.z, bb.w };
            #pragma unroll
            for (int i = 0; i < 8; ++i)
                #pragma unroll
                for (int j = 0; j < 8; ++j)
                    acc[i][j] = fmaf(xs[i], bs[j], acc[i][j]);
        }
    }

    // ---- epilogue: acc rows are n-contiguous -> float4 stores
    float* dst = part + ((size_t)(b * NH + wave) * NBLK + blk) * 4096;
    #pragma unroll
    for (int i = 0; i < 8; ++i) {
        float4 lo = make_float4(acc[i][0], acc[i][1], acc[i][2], acc[i][3]);
        float4 hi = make_float4(acc[i][4], acc[i][5], acc[i][6], acc[i][7]);
        *(float4*)&dst[(p0F + i) * 64 + n0F]     = lo;
        *(float4*)&dst[(p0F + i) * 64 + n0F + 4] = hi;
    }
}

// ---------------------------------------------------------------------------
// k_scales: suffix-exp over chunk totals, per (b,h)
// ---------------------------------------------------------------------------
__global__ void k_scales(const float* __restrict__ blockA, float* __restrict__ scale,
                         int nblk)
{
    const int bh = blockIdx.x * blockDim.x + threadIdx.x;
    if (bh < BATCH * NH) {
        float run = 0.f;
        for (int c2 = nblk - 1; c2 >= 0; --c2) {
            scale[bh * nblk + c2] = __expf(run);
            run += blockA[bh * nblk + c2];
        }
    }
}

// ---------------------------------------------------------------------------
// k_combine: out[bh,p,n] = sum_c scale[bh,c] * part[bh,c,p,n]
// ---------------------------------------------------------------------------
__global__ __launch_bounds__(256)
void k_combine(const float* __restrict__ part, const float* __restrict__ scale,
               float* __restrict__ out, int nblk)
{
    const int idx = blockIdx.x * 256 + threadIdx.x;   // 0..524287
    const int bh  = idx >> 12;
    const int e   = idx & 4095;
    float r = 0.f;
    for (int q = 0; q < nblk; ++q)
        r += scale[bh * nblk + q] * part[((size_t)bh * nblk + q) * 4096 + e];
    out[idx] = r;
}

// ---------------------------------------------------------------------------
extern "C" void kernel_launch(void* const* d_in, const int* in_sizes, int n_in,
                              void* d_out, int out_size, void* d_ws, size_t ws_size,
                              hipStream_t stream)
{
    const float* X = (const float*)d_in[0];
    const float* A = (const float*)d_in[1];
    const float* B = (const float*)d_in[2];
    float* out     = (float*)d_out;

    // ws need for NBLK chunks: part (8*16*NBLK*4096 f32) + blockA + scale
    const size_t need32 = ((size_t)BATCH * NH * 32 * 4096 + 2ull * BATCH * NH * 32) * 4;
    const int nblk = (ws_size >= need32) ? 32 : 16;

    float* part   = (float*)d_ws;
    float* blockA = part + (size_t)BATCH * NH * nblk * 4096;
    float* scale  = blockA + (size_t)BATCH * NH * nblk;

    if (nblk == 32)
        hipLaunchKernelGGL((k_partial<32>), dim3(BATCH * 32), dim3(NTHR), 0, stream,
                           X, A, B, part, blockA);
    else
        hipLaunchKernelGGL((k_partial<16>), dim3(BATCH * 16), dim3(NTHR), 0, stream,
                           X, A, B, part, blockA);

    hipLaunchKernelGGL(k_scales, dim3(1), dim3(128), 0, stream, blockA, scale, nblk);
    hipLaunchKernelGGL(k_combine, dim3((BATCH * NH * 4096) / 256), dim3(256), 0, stream,
                       part, scale, out, nblk);
}